// Round 4
// baseline (490.803 us; speedup 1.0000x reference)
//
#include <hip/hip_runtime.h>
#include <hip/hip_fp16.h>
#include <math.h>

#define FIXLEN 30.0f
#define BETA   0.25f

typedef unsigned short u16;
typedef unsigned int   u32;
typedef unsigned long long u64;
typedef _Float16 half8 __attribute__((ext_vector_type(8)));
typedef float    f32x4 __attribute__((ext_vector_type(4)));

// ---------------- ws layout (bytes) ----------------
#define NRM_OFF    0         // f[64]
#define NRMMAX_OFF 256       // f[64]
#define CST_OFF    512       // f[16]: 0=scale,1=inv_s,2=EPS2,3=maxNrm
#define CNT_OFF    576       // i[1]
#define DIFF_OFF   1024      // f[256]
#define ZMAX_OFF   2048      // f[1024]
#define EMAXL_OFF  6144      // f[2048]
#define EMAXE_OFF  14336     // f[2048]
#define E2_OFF     22528     // f[16384]
#define BESTN_OFF  88064     // i[16384]
#define LIST_OFF   153600    // i[16384]
#define PV1_OFF    219136    // u64[8*16384]
#define PVB2_OFF   1267712   // f[8*16384]
#define ZH_OFF     1792000   // half[16384*256]
#define EH_OFF     10180608  // half[16384*256]  -> total 18569216

__device__ inline u32 fkey(float d) {
    u32 b = __float_as_uint(d);
    return (b & 0x80000000u) ? ~b : (b | 0x80000000u);
}
__device__ inline float fdec(u32 k) {
    u32 b = (k & 0x80000000u) ? (k & 0x7FFFFFFFu) : ~k;
    return __uint_as_float(b);
}
__device__ inline void gl_lds16(const void* g, void* l) {
    __builtin_amdgcn_global_load_lds(
        (const __attribute__((address_space(1))) unsigned int*)g,
        (__attribute__((address_space(3))) unsigned int*)l, 16, 0, 0);
}

// ---------------- K1: per-token channel L2 norms (sum + max partials) ----------------
__global__ void k_norms(const float* __restrict__ z, float* __restrict__ nrm_part,
                        float* __restrict__ nrmmax_part) {
    int t = blockIdx.x * 256 + threadIdx.x;   // grid = 64
    int b = t >> 10, tl = t & 1023;
    const float* zp = z + (size_t)b * 262144 + tl;
    float s = 0.f;
    #pragma unroll 8
    for (int c = 0; c < 256; ++c) {
        float v = zp[(size_t)c << 10];
        s = fmaf(v, v, s);
    }
    float nrm = sqrtf(s);
    __shared__ float rs[256], rm[256];
    rs[threadIdx.x] = nrm; rm[threadIdx.x] = nrm;
    __syncthreads();
    for (int off = 128; off > 0; off >>= 1) {
        if (threadIdx.x < off) {
            rs[threadIdx.x] += rs[threadIdx.x + off];
            rm[threadIdx.x] = fmaxf(rm[threadIdx.x], rm[threadIdx.x + off]);
        }
        __syncthreads();
    }
    if (threadIdx.x == 0) { nrm_part[blockIdx.x] = rs[0]; nrmmax_part[blockIdx.x] = rm[0]; }
}

// ---------------- K2: emb -> fp16 plane + e2 + residual-norm maxes ----------------
__global__ void k_split_e(const float* __restrict__ emb, u16* __restrict__ eh,
                          float* __restrict__ e2, float* __restrict__ emaxl,
                          float* __restrict__ emaxe) {
    int gidx = blockIdx.x * 256 + threadIdx.x;   // grid = 2048
    int n = gidx >> 5;
    int c8 = (gidx & 31) * 8;
    const float* ep = emb + (size_t)n * 256 + c8;
    float4 v0 = *(const float4*)ep;
    float4 v1 = *(const float4*)(ep + 4);
    float vv[8] = {v0.x, v0.y, v0.z, v0.w, v1.x, v1.y, v1.z, v1.w};
    u32 pw[4];
    float s2 = 0.f, r2 = 0.f;
    #pragma unroll
    for (int k = 0; k < 4; ++k) {
        __half h0 = __float2half(vv[2 * k]);
        __half h1 = __float2half(vv[2 * k + 1]);
        float r0 = vv[2 * k] - __half2float(h0);
        float r1 = vv[2 * k + 1] - __half2float(h1);
        s2 = fmaf(vv[2 * k], vv[2 * k], s2);
        s2 = fmaf(vv[2 * k + 1], vv[2 * k + 1], s2);
        r2 = fmaf(r0, r0, r2);
        r2 = fmaf(r1, r1, r2);
        pw[k] = (u32)__half_as_ushort(h0) | ((u32)__half_as_ushort(h1) << 16);
    }
    *(uint4*)(eh + (size_t)n * 256 + c8) = make_uint4(pw[0], pw[1], pw[2], pw[3]);
    #pragma unroll
    for (int off = 16; off > 0; off >>= 1) {
        s2 += __shfl_down(s2, off, 32);
        r2 += __shfl_down(r2, off, 32);
    }
    __shared__ float L1[8], L2[8];
    if ((threadIdx.x & 31) == 0) {
        e2[n] = s2;
        L1[threadIdx.x >> 5] = r2;
        L2[threadIdx.x >> 5] = s2;
    }
    __syncthreads();
    if (threadIdx.x == 0) {
        float a = 0.f, bmax = 0.f;
        #pragma unroll
        for (int i = 0; i < 8; ++i) { a = fmaxf(a, L1[i]); bmax = fmaxf(bmax, L2[i]); }
        emaxl[blockIdx.x] = a;
        emaxe[blockIdx.x] = bmax;
    }
}

// ---------------- K3: z -> fp16(-2*z/30) plane (transpose) + per-token residual-sq partial max ----
__global__ void k_split_z(const float* __restrict__ z, u16* __restrict__ zh,
                          float* __restrict__ zmax_part) {
    int bi = blockIdx.x;                     // grid = 1024
    int b = bi >> 6, rest = bi & 63;
    int c0 = (rest >> 4) * 64, s0 = (rest & 15) * 64;
    __shared__ float ld[64][65];
    __shared__ float red2[64][4];
    __shared__ float rmax[64];
    int tid = threadIdx.x;
    #pragma unroll
    for (int p = 0; p < 16; ++p) {
        int idx = p * 256 + tid;
        int cc = idx >> 6, ss = idx & 63;
        ld[cc][ss] = z[(size_t)b * 262144 + (size_t)(c0 + cc) * 1024 + s0 + ss];
    }
    __syncthreads();
    int ss2 = tid >> 2, cq = tid & 3;
    int t = b * 1024 + s0 + ss2;
    float r2 = 0.f;
    u32 pk[8];
    #pragma unroll
    for (int k = 0; k < 8; ++k) pk[k] = 0;
    #pragma unroll
    for (int j = 0; j < 16; ++j) {
        float v = ld[cq * 16 + j][ss2] * (1.0f / 30.0f);
        __half h = __float2half(v);
        float vh = __half2float(h);
        float r = v - vh;
        r2 = fmaf(r, r, r2);
        __half hs = __float2half(-2.0f * vh);   // exact power-of-2 scale
        pk[j >> 1] |= ((u32)__half_as_ushort(hs)) << ((j & 1) * 16);
    }
    u16* dst = zh + (size_t)t * 256 + c0 + cq * 16;
    *(uint4*)dst = make_uint4(pk[0], pk[1], pk[2], pk[3]);
    *(uint4*)(dst + 8) = make_uint4(pk[4], pk[5], pk[6], pk[7]);
    red2[ss2][cq] = r2;
    __syncthreads();
    if (tid < 64) rmax[tid] = red2[tid][0] + red2[tid][1] + red2[tid][2] + red2[tid][3];
    __syncthreads();
    for (int off = 32; off > 0; off >>= 1) {
        if (tid < off) rmax[tid] = fmaxf(rmax[tid], rmax[tid + off]);
        __syncthreads();
    }
    if (tid == 0) zmax_part[bi] = rmax[0];
}

// ---------------- K4: merged scalar pass: scale + EPS2 + cnt=0 ----------------
__global__ void k_scalars(const float* __restrict__ nrm_part, const float* __restrict__ nrmmax_part,
                          const float* __restrict__ zmax_part, const float* __restrict__ emaxl,
                          const float* __restrict__ emaxe, float* __restrict__ cst,
                          int* __restrict__ cnt) {
    int tid = threadIdx.x;  // 256
    float s = (tid < 64) ? nrm_part[tid] : 0.f;
    float m = (tid < 64) ? nrmmax_part[tid] : 0.f;
    float zm = 0.f, el = 0.f, ee = 0.f;
    for (int i = tid; i < 1024; i += 256) zm = fmaxf(zm, zmax_part[i]);
    for (int i = tid; i < 2048; i += 256) { el = fmaxf(el, emaxl[i]); ee = fmaxf(ee, emaxe[i]); }
    __shared__ float S[256], M[256], Z[256], L[256], E[256];
    S[tid] = s; M[tid] = m; Z[tid] = zm; L[tid] = el; E[tid] = ee;
    __syncthreads();
    for (int off = 128; off > 0; off >>= 1) {
        if (tid < off) {
            S[tid] += S[tid + off];
            M[tid] = fmaxf(M[tid], M[tid + off]);
            Z[tid] = fmaxf(Z[tid], Z[tid + off]);
            L[tid] = fmaxf(L[tid], L[tid + off]);
            E[tid] = fmaxf(E[tid], E[tid + off]);
        }
        __syncthreads();
    }
    if (tid == 0) {
        float pre_len = S[0] * (1.0f / 16384.0f);
        float scale = (pre_len >= FIXLEN) ? (FIXLEN / pre_len) : 1.0f;
        cst[0] = scale;
        cst[1] = 1.0f / scale;
        cst[3] = M[0];
        float maxA  = M[0] * (1.0f / 30.0f);
        float maxEl = sqrtf(L[0]);
        float maxE  = sqrtf(E[0]);
        float maxZl = 2.0f * sqrtf(Z[0]);
        float eps = 2.0f * (maxA * maxEl + maxZl * maxE + maxZl * maxEl) + 0.03f;
        cst[2] = 2.0f * eps;
        cnt[0] = 0;
    }
}

// ---------------- K5: fp16 MFMA GEMM, counted-vmcnt pipeline with read/MFMA overlap ------------
// 512 threads = 8 waves (2M x 4N), wave tile 64 tok x 128 emb.  __launch_bounds__(512,1):
// 256-VGPR budget (round-3 failure was a 128-VGPR cap -> scratch spill, WRITE_SIZE 113 MB).
// LDS 136 KB: A plane 64 KB resident + B dbuf 2 x 32 KB (512 emb x K=32) + e2 8 KB.
// Loop rotated so slice s+1's frag ds_reads are issued from the certified other buffer
// DURING slice s's MFMA cluster (B[0..3] dead after MFMA group1, A after group2 -> no frag
// double-buffer, no extra VGPRs).  Steady state: lgkm(0); bar; stage(s+2)->bcur; vmcnt(4)
// [s+1 landed, s+2 in flight]; bar; MFMA tj0-3; read B'(lo); MFMA tj4-7; read A'+B'(hi).
// Chunk-boundary argmin (packed keys, 3 VALU/out) runs under the read latency.
__launch_bounds__(512, 1)
__global__ void k_mfma(const u16* __restrict__ zh, const u16* __restrict__ eh,
                       const float* __restrict__ e2g, const float* __restrict__ cst,
                       u64* __restrict__ pv1, float* __restrict__ pvb2) {
    __shared__ __align__(16) char lds[139264];
    char* sAb = lds;                      // 64 KB: [128 rows][32 slots16], slot^=(row&7) low3
    char* sB0 = lds + 65536;              // 32 KB: [512 rows][4 slots16], slot^=((row>>1)&3)
    char* sB1 = lds + 98304;              // 32 KB
    float* e2s = (float*)(lds + 131072);  // 8 KB

    int part = blockIdx.x & 7;            // XCD-aligned: one B-part per XCD L2
    int tokT = blockIdx.x >> 3;           // 0..127
    int t0 = tokT * 128;
    int nbase = part * 2048;
    int tid = threadIdx.x, w = tid >> 6, lane = tid & 63;
    int ml = lane & 15, q = lane >> 4;
    int wm0 = (w >> 2) * 64;              // 2 M groups
    int wn0 = (w & 3) * 128;              // 4 N groups within 512-emb chunk
    int x7 = ml & 7;
    int xb = (ml >> 1) & 3;

    float inv_s = cst[1];
    asm volatile("s_waitcnt vmcnt(0) lgkmcnt(0)" ::: "memory");  // cst out of the count stream

    // ---- prologue: stage A plane (8 granules/thread), source-XOR swizzle ----
    #pragma unroll
    for (int i = 0; i < 8; ++i) {
        int el = i * 512 + tid;
        int row = el >> 5, j = el & 31;
        int jsrc = (j & 24) | ((j & 7) ^ (row & 7));
        gl_lds16(zh + (size_t)(t0 + row) * 256 + jsrc * 8, sAb + el * 16);
    }
    // e2 part (2048 floats, linear)
    gl_lds16(e2g + nbase + tid * 4, (char*)e2s + tid * 16);

    u32 boff[4];
    #pragma unroll
    for (int i = 0; i < 4; ++i) {
        int el = i * 512 + tid;
        int row = el >> 2, j = el & 3;
        int jsrc = j ^ ((row >> 1) & 3);
        boff[i] = (u32)((nbase + row) * 512 + jsrc * 16);
    }
    const char* ehb = (const char*)eh;

    // stage slices 0 -> buf0, 1 -> buf1
    #pragma unroll
    for (int i = 0; i < 4; ++i)
        gl_lds16(ehb + boff[i], sB0 + (i * 512 + tid) * 16);
    #pragma unroll
    for (int i = 0; i < 4; ++i)
        gl_lds16(ehb + boff[i] + 64u, sB1 + (i * 512 + tid) * 16);

    asm volatile("s_waitcnt vmcnt(4)" ::: "memory");   // A+e2+slice0 done; slice1 in flight
    __builtin_amdgcn_sched_barrier(0);
    __builtin_amdgcn_s_barrier();

    float b1[16], b2[16];
    #pragma unroll
    for (int k = 0; k < 16; ++k) { b1[k] = 3.4e38f; b2[k] = 3.4e38f; }

    f32x4 acc[4][8];
    half8 A[4], B[8];
    float e2l[8];
    int ncol0 = nbase + wn0 + ml;
    int slotB = q ^ xb;

    // ---- pre-read frags for slice 0 + e2 bias for chunk 0 ----
    {
        #pragma unroll
        for (int tj = 0; tj < 8; ++tj)
            B[tj] = *(const half8*)(sB0 + (wn0 + tj * 16 + ml) * 64 + slotB * 16);
        int slotA = q ^ x7;   // ks=0
        #pragma unroll
        for (int ti = 0; ti < 4; ++ti)
            A[ti] = *(const half8*)(sAb + (wm0 + ti * 16 + ml) * 512 + slotA * 16);
        #pragma unroll
        for (int tj = 0; tj < 8; ++tj)
            e2l[tj] = e2s[wn0 + tj * 16 + ml];
    }

    #pragma unroll 1
    for (int c = 0; c < 4; ++c) {
        #pragma unroll
        for (int ks = 0; ks < 8; ++ks) {
            char* bcur  = (ks & 1) ? sB1 : sB0;
            char* bnext = (ks & 1) ? sB0 : sB1;
            // frags for this slice (issued last iteration) complete; then buffer handoff
            asm volatile("s_waitcnt lgkmcnt(0)" ::: "memory");
            __builtin_amdgcn_sched_barrier(0);
            __builtin_amdgcn_s_barrier();          // #1: all waves done reading bcur
            // stage slice s+2 into bcur
            if (c < 3 || ks < 6) {
                int cc2 = (ks >= 6) ? c + 1 : c;
                const int kk2 = (ks + 2) & 7;
                u32 add = (u32)(cc2 * 262144 + kk2 * 64);
                #pragma unroll
                for (int i = 0; i < 4; ++i)
                    gl_lds16(ehb + boff[i] + add, bcur + (i * 512 + tid) * 16);
            }
            // counted wait: slice s+1 landed (s+2 stays in flight)
            if (c < 3 || ks < 6) {
                asm volatile("s_waitcnt vmcnt(4)" ::: "memory");
            } else if (ks == 6) {
                asm volatile("s_waitcnt vmcnt(0)" ::: "memory");   // tail: slice 31
            }
            __builtin_amdgcn_sched_barrier(0);
            __builtin_amdgcn_s_barrier();          // #2: bnext fully valid for all waves
            // ---- MFMA group 1 (tj 0..3); ks==0 seeds acc with e2 bias as C ----
            __builtin_amdgcn_s_setprio(1);
            if (ks == 0) {
                #pragma unroll
                for (int tj = 0; tj < 4; ++tj) {
                    float bv = e2l[tj] * inv_s;
                    f32x4 cb = {bv, bv, bv, bv};
                    #pragma unroll
                    for (int ti = 0; ti < 4; ++ti)
                        acc[ti][tj] = __builtin_amdgcn_mfma_f32_16x16x32_f16(A[ti], B[tj], cb, 0, 0, 0);
                }
            } else {
                #pragma unroll
                for (int ti = 0; ti < 4; ++ti)
                    #pragma unroll
                    for (int tj = 0; tj < 4; ++tj)
                        acc[ti][tj] = __builtin_amdgcn_mfma_f32_16x16x32_f16(A[ti], B[tj], acc[ti][tj], 0, 0, 0);
            }
            // ---- read B[0..3] for slice s+1 (B[0..3] dead after group 1) ----
            if (c < 3 || ks < 7) {
                #pragma unroll
                for (int tj = 0; tj < 4; ++tj)
                    B[tj] = *(const half8*)(bnext + (wn0 + tj * 16 + ml) * 64 + slotB * 16);
            }
            // ---- MFMA group 2 (tj 4..7) ----
            if (ks == 0) {
                #pragma unroll
                for (int tj = 4; tj < 8; ++tj) {
                    float bv = e2l[tj] * inv_s;
                    f32x4 cb = {bv, bv, bv, bv};
                    #pragma unroll
                    for (int ti = 0; ti < 4; ++ti)
                        acc[ti][tj] = __builtin_amdgcn_mfma_f32_16x16x32_f16(A[ti], B[tj], cb, 0, 0, 0);
                }
            } else {
                #pragma unroll
                for (int ti = 0; ti < 4; ++ti)
                    #pragma unroll
                    for (int tj = 4; tj < 8; ++tj)
                        acc[ti][tj] = __builtin_amdgcn_mfma_f32_16x16x32_f16(A[ti], B[tj], acc[ti][tj], 0, 0, 0);
            }
            __builtin_amdgcn_s_setprio(0);
            // ---- read A + B[4..7] for slice s+1 (A dead after group 2) + next e2 ----
            if (c < 3 || ks < 7) {
                const int ksn = (ks + 1) & 7;
                int slotA = (ksn >> 1) * 8 + ((((ksn & 1) * 4) + q) ^ x7);
                #pragma unroll
                for (int tj = 4; tj < 8; ++tj)
                    B[tj] = *(const half8*)(bnext + (wn0 + tj * 16 + ml) * 64 + slotB * 16);
                #pragma unroll
                for (int ti = 0; ti < 4; ++ti)
                    A[ti] = *(const half8*)(sAb + (wm0 + ti * 16 + ml) * 512 + slotA * 16);
                if (ks == 7) {
                    #pragma unroll
                    for (int tj = 0; tj < 8; ++tj)
                        e2l[tj] = e2s[(c + 1) * 512 + wn0 + tj * 16 + ml];
                }
            }
            // ---- chunk-boundary argmin: pure VALU, overlaps the reads above ----
            if (ks == 7) {
                u32 code0 = (u32)(c * 8);
                #pragma unroll
                for (int ti = 0; ti < 4; ++ti)
                    #pragma unroll
                    for (int r = 0; r < 4; ++r) {
                        int k = ti * 4 + r;
                        #pragma unroll
                        for (int tj = 0; tj < 8; ++tj) {
                            u32 kb = (__float_as_uint(acc[ti][tj][r]) & 0xFFFFFFE0u) | (code0 + (u32)tj);
                            float key = __uint_as_float(kb);
                            b2[k] = __builtin_amdgcn_fmed3f(key, b1[k], b2[k]);
                            b1[k] = fminf(b1[k], key);
                        }
                    }
            }
        }
    }

    // decode packed indices: code = c*8 + tj  ->  n = ncol0 + c*512 + tj*16
    int i1[16];
    #pragma unroll
    for (int k = 0; k < 16; ++k) {
        u32 cc = __float_as_uint(b1[k]) & 31u;
        i1[k] = ncol0 + (int)((cc >> 3) << 9) + (int)((cc & 7) << 4);
    }
    // cross-lane merge over ml (masks 1,2,4,8); ties fall to refine via b2
    #pragma unroll
    for (int k = 0; k < 16; ++k) {
        #pragma unroll
        for (int m = 1; m < 16; m <<= 1) {
            float o1 = __shfl_xor(b1[k], m);
            int   oi = __shfl_xor(i1[k], m);
            float o2 = __shfl_xor(b2[k], m);
            float big = fmaxf(b1[k], o1);
            b2[k] = fminf(fminf(b2[k], o2), big);
            bool cnd = o1 < b1[k];
            i1[k] = cnd ? oi : i1[k];
            b1[k] = fminf(b1[k], o1);
        }
    }
    __syncthreads();   // all LDS compute done; overlay merge arrays on buf0
    float* m1s = (float*)sB0;              // [3][128]
    int*   mis = (int*)(sB0 + 1536);       // [3][128]
    float* m2s = (float*)(sB0 + 3072);     // [3][128]
    int g = w & 3;
    if (g > 0 && ml == 0) {
        #pragma unroll
        for (int ti = 0; ti < 4; ++ti)
            #pragma unroll
            for (int r = 0; r < 4; ++r) {
                int mr = wm0 + ti * 16 + q * 4 + r;
                int k = ti * 4 + r;
                int o = (g - 1) * 128 + mr;
                m1s[o] = b1[k]; mis[o] = i1[k]; m2s[o] = b2[k];
            }
    }
    __syncthreads();
    if (g == 0 && ml == 0) {
        #pragma unroll
        for (int ti = 0; ti < 4; ++ti)
            #pragma unroll
            for (int r = 0; r < 4; ++r) {
                int mr = wm0 + ti * 16 + q * 4 + r;
                int k = ti * 4 + r;
                float f1 = b1[k], f2 = b2[k]; int fi = i1[k];
                #pragma unroll
                for (int gg = 0; gg < 3; ++gg) {
                    float a1 = m1s[gg * 128 + mr];
                    int   ai = mis[gg * 128 + mr];
                    float a2 = m2s[gg * 128 + mr];
                    float big = fmaxf(f1, a1);
                    f2 = fminf(fminf(f2, a2), big);
                    if (a1 < f1) { f1 = a1; fi = ai; }
                }
                int t = t0 + mr;
                pv1[(size_t)part * 16384 + t] = ((u64)fkey(f1) << 32) | (u32)fi;
                pvb2[(size_t)part * 16384 + t] = f2;
            }
    }
}

// ---------------- K6: certify per token; build uncertified list ----------------
__global__ void k_refine(const u64* __restrict__ pv1, const float* __restrict__ pvb2,
                         const float* __restrict__ cst, int* __restrict__ bestn,
                         int* __restrict__ list, int* __restrict__ cnt) {
    int t = blockIdx.x * 256 + threadIdx.x;   // grid 64
    float EPS2 = cst[2];
    float amin = 3.4e38f, sec = 3.4e38f; int wi = 0;
    #pragma unroll
    for (int p = 0; p < 8; ++p) {
        u64 u = pv1[(size_t)p * 16384 + t];
        float d1 = fdec((u32)(u >> 32));
        float d2 = pvb2[(size_t)p * 16384 + t];
        if (d1 < amin) { sec = fminf(fminf(sec, amin), d2); amin = d1; wi = (int)(u32)(u & 0xFFFFFFFFull); }
        else sec = fminf(sec, d1);
    }
    bool cert = sec > amin + EPS2;
    if (cert) bestn[t] = wi;
    u64 mask = __ballot(!cert);
    if (mask) {
        int lane = threadIdx.x & 63;
        int leader = __ffsll((long long)mask) - 1;
        int base = 0;
        if (lane == leader) base = atomicAdd(cnt, __popcll(mask));
        base = __shfl(base, leader);
        if (!cert) {
            int rank = __popcll(mask & ((1ull << lane) - 1ull));
            list[base + rank] = t;
        }
    }
}

// ---------------- K7: exact refinement of uncertified tokens, one wave per token ----------------
__global__ void k_refine2(const float* __restrict__ z, const float* __restrict__ emb,
                          const float* __restrict__ e2, const u64* __restrict__ pv1,
                          const float* __restrict__ pvb2, const float* __restrict__ cst,
                          const int* __restrict__ cnt, const int* __restrict__ list,
                          int* __restrict__ bestn) {
    __shared__ float az[4][256];
    int w = threadIdx.x >> 6, lane = threadIdx.x & 63;
    int wid = blockIdx.x * 4 + w;              // grid 64 -> 256 waves
    int C = cnt[0];
    float inv_s = cst[1], EPS2 = cst[2];
    for (int it = wid; it < C; it += 256) {
        int t = list[it];
        int b = t >> 10, hw = t & 1023;
        #pragma unroll
        for (int j = 0; j < 4; ++j)
            az[w][lane + 64 * j] = z[(size_t)b * 262144 + (size_t)(lane + 64 * j) * 1024 + hw] * (1.0f / 30.0f);
        float pb1[8], pb2[8]; int pi1[8];
        float amin = 3.4e38f;
        #pragma unroll
        for (int p = 0; p < 8; ++p) {
            u64 u = pv1[(size_t)p * 16384 + t];
            pb1[p] = fdec((u32)(u >> 32));
            pi1[p] = (int)(u32)(u & 0xFFFFFFFFull);
            pb2[p] = pvb2[(size_t)p * 16384 + t];
            amin = fminf(amin, pb1[p]);
        }
        float thresh = amin + EPS2;
        float bestv = 3.4e38f; int bi = 0x7fffffff;
        for (int p = 0; p < 8; ++p) {
            if (pb2[p] <= thresh) {
                for (int it2 = 0; it2 < 32; ++it2) {
                    int n = p * 2048 + it2 * 64 + lane;
                    const float4* ep = (const float4*)(emb + (size_t)n * 256);
                    float s = 0.f;
                    #pragma unroll 16
                    for (int kk = 0; kk < 64; ++kk) {
                        float4 a4 = *(const float4*)&az[w][kk * 4];
                        float4 e4 = ep[kk];
                        s = fmaf(a4.x, e4.x, s); s = fmaf(a4.y, e4.y, s);
                        s = fmaf(a4.z, e4.z, s); s = fmaf(a4.w, e4.w, s);
                    }
                    float d = fmaf(-2.0f, s, e2[n] * inv_s);
                    if (d < bestv || (d == bestv && n < bi)) { bestv = d; bi = n; }
                }
            } else if (pb1[p] <= thresh) {
                int n = pi1[p];
                float4 a4 = *(const float4*)&az[w][lane * 4];
                float4 e4 = *(const float4*)&emb[(size_t)n * 256 + lane * 4];
                float s = a4.x * e4.x + a4.y * e4.y + a4.z * e4.z + a4.w * e4.w;
                #pragma unroll
                for (int m = 1; m < 64; m <<= 1) s += __shfl_xor(s, m);
                float d = fmaf(-2.0f, s, e2[n] * inv_s);
                if (d < bestv || (d == bestv && n < bi)) { bestv = d; bi = n; }
            }
        }
        #pragma unroll
        for (int m = 1; m < 64; m <<= 1) {
            float ov = __shfl_xor(bestv, m);
            int oi = __shfl_xor(bi, m);
            if (ov < bestv || (ov == bestv && oi < bi)) { bestv = ov; bi = oi; }
        }
        if (lane == 0) bestn[t] = bi;
    }
}

// ---------------- K8: emit z_q, idx, diff partials ----------------
__global__ void k_emit(const float* __restrict__ z, const float* __restrict__ emb,
                       const float* __restrict__ cst, const int* __restrict__ bestn,
                       float* __restrict__ out, float* __restrict__ diff_part) {
    int blk = blockIdx.x;                 // 256
    int cq = blk >> 6, sub = blk & 63;
    int b = sub >> 2;
    int tl = (sub & 3) * 256 + threadIdx.x;
    int t = b * 1024 + tl;
    int bi = bestn[t];
    if (cq == 0) out[4194305 + t] = (float)bi;
    float scale = cst[0];
    const float* er = emb + (size_t)bi * 256 + cq * 64;
    const float* zr = z + (size_t)b * 262144 + (size_t)cq * 65536 + tl;
    float* orow = out + (size_t)b * 262144 + (size_t)cq * 65536 + tl;
    float ds = 0.f;
    #pragma unroll 8
    for (int j = 0; j < 64; ++j) {
        float qv = er[j] * FIXLEN;
        float zt = zr[(size_t)j << 10] * scale;
        float dd = qv - zt;
        ds = fmaf(dd, dd, ds);
        orow[(size_t)j << 10] = qv;
    }
    __shared__ float red[256];
    red[threadIdx.x] = ds;
    __syncthreads();
    for (int off = 128; off > 0; off >>= 1) {
        if (threadIdx.x < off) red[threadIdx.x] += red[threadIdx.x + off];
        __syncthreads();
    }
    if (threadIdx.x == 0) diff_part[blk] = red[0];
}

// ---------------- K9: finalize diff ----------------
__global__ void k_diff(const float* __restrict__ diff_part, float* __restrict__ out) {
    int tid = threadIdx.x;   // 256
    __shared__ float red[256];
    red[tid] = diff_part[tid];
    __syncthreads();
    for (int off = 128; off > 0; off >>= 1) {
        if (tid < off) red[tid] += red[tid + off];
        __syncthreads();
    }
    if (tid == 0) out[4194304] = BETA * red[0] / 4194304.0f;
}

extern "C" void kernel_launch(void* const* d_in, const int* in_sizes, int n_in,
                              void* d_out, int out_size, void* d_ws, size_t ws_size,
                              hipStream_t stream) {
    const float* z   = (const float*)d_in[0];
    const float* emb = (const float*)d_in[1];
    float* out = (float*)d_out;
    char* wsb = (char*)d_ws;

    float* nrm_part    = (float*)(wsb + NRM_OFF);
    float* nrmmax_part = (float*)(wsb + NRMMAX_OFF);
    float* cst         = (float*)(wsb + CST_OFF);
    int*   cnt         = (int*)(wsb + CNT_OFF);
    float* diff_part   = (float*)(wsb + DIFF_OFF);
    float* zmax_part   = (float*)(wsb + ZMAX_OFF);
    float* emaxl       = (float*)(wsb + EMAXL_OFF);
    float* emaxe       = (float*)(wsb + EMAXE_OFF);
    float* e2          = (float*)(wsb + E2_OFF);
    int*   bestn       = (int*)(wsb + BESTN_OFF);
    int*   list        = (int*)(wsb + LIST_OFF);
    u64*   pv1         = (u64*)(wsb + PV1_OFF);
    float* pvb2        = (float*)(wsb + PVB2_OFF);
    u16*   zh          = (u16*)(wsb + ZH_OFF);
    u16*   eh          = (u16*)(wsb + EH_OFF);

    k_norms<<<64, 256, 0, stream>>>(z, nrm_part, nrmmax_part);
    k_split_e<<<2048, 256, 0, stream>>>(emb, eh, e2, emaxl, emaxe);
    k_split_z<<<1024, 256, 0, stream>>>(z, zh, zmax_part);
    k_scalars<<<1, 256, 0, stream>>>(nrm_part, nrmmax_part, zmax_part, emaxl, emaxe, cst, cnt);
    k_mfma<<<1024, 512, 0, stream>>>(zh, eh, e2, cst, pv1, pvb2);
    k_refine<<<64, 256, 0, stream>>>(pv1, pvb2, cst, bestn, list, cnt);
    k_refine2<<<64, 256, 0, stream>>>(z, emb, e2, pv1, pvb2, cst, cnt, list, bestn);
    k_emit<<<256, 256, 0, stream>>>(z, emb, cst, bestn, out, diff_part);
    k_diff<<<1, 256, 0, stream>>>(diff_part, out);
}

// Round 5
// 284.523 us; speedup vs baseline: 1.7250x; 1.7250x over previous
//
#include <hip/hip_runtime.h>
#include <hip/hip_fp16.h>
#include <math.h>

#define FIXLEN 30.0f
#define BETA   0.25f

typedef unsigned short u16;
typedef unsigned int   u32;
typedef unsigned long long u64;
typedef _Float16 half8 __attribute__((ext_vector_type(8)));
typedef float    f32x4 __attribute__((ext_vector_type(4)));

// ---------------- ws layout (bytes) ----------------
#define NRM_OFF    0         // f[64]
#define NRMMAX_OFF 256       // f[64]
#define CST_OFF    512       // f[16]: 0=scale,1=inv_s,2=EPS2,3=maxNrm
#define CNT_OFF    576       // i[1]
#define DIFF_OFF   1024      // f[256]
#define ZMAX_OFF   2048      // f[1024]
#define EMAXL_OFF  6144      // f[2048]
#define EMAXE_OFF  14336     // f[2048]
#define E2_OFF     22528     // f[16384]
#define BESTN_OFF  88064     // i[16384]
#define LIST_OFF   153600    // i[16384]
#define PV1_OFF    219136    // u64[8*16384]
#define PVB2_OFF   1267712   // f[8*16384]
#define ZH_OFF     1792000   // half[16384*256]
#define EH_OFF     10180608  // half[16384*256]  -> total 18569216

__device__ inline u32 fkey(float d) {
    u32 b = __float_as_uint(d);
    return (b & 0x80000000u) ? ~b : (b | 0x80000000u);
}
__device__ inline float fdec(u32 k) {
    u32 b = (k & 0x80000000u) ? (k & 0x7FFFFFFFu) : ~k;
    return __uint_as_float(b);
}
__device__ inline void gl_lds16(const void* g, void* l) {
    __builtin_amdgcn_global_load_lds(
        (const __attribute__((address_space(1))) unsigned int*)g,
        (__attribute__((address_space(3))) unsigned int*)l, 16, 0, 0);
}

// ---------------- K1: per-token channel L2 norms (sum + max partials) ----------------
__global__ void k_norms(const float* __restrict__ z, float* __restrict__ nrm_part,
                        float* __restrict__ nrmmax_part) {
    int t = blockIdx.x * 256 + threadIdx.x;   // grid = 64
    int b = t >> 10, tl = t & 1023;
    const float* zp = z + (size_t)b * 262144 + tl;
    float s = 0.f;
    #pragma unroll 8
    for (int c = 0; c < 256; ++c) {
        float v = zp[(size_t)c << 10];
        s = fmaf(v, v, s);
    }
    float nrm = sqrtf(s);
    __shared__ float rs[256], rm[256];
    rs[threadIdx.x] = nrm; rm[threadIdx.x] = nrm;
    __syncthreads();
    for (int off = 128; off > 0; off >>= 1) {
        if (threadIdx.x < off) {
            rs[threadIdx.x] += rs[threadIdx.x + off];
            rm[threadIdx.x] = fmaxf(rm[threadIdx.x], rm[threadIdx.x + off]);
        }
        __syncthreads();
    }
    if (threadIdx.x == 0) { nrm_part[blockIdx.x] = rs[0]; nrmmax_part[blockIdx.x] = rm[0]; }
}

// ---------------- K2: emb -> fp16 plane + e2 + residual-norm maxes ----------------
__global__ void k_split_e(const float* __restrict__ emb, u16* __restrict__ eh,
                          float* __restrict__ e2, float* __restrict__ emaxl,
                          float* __restrict__ emaxe) {
    int gidx = blockIdx.x * 256 + threadIdx.x;   // grid = 2048
    int n = gidx >> 5;
    int c8 = (gidx & 31) * 8;
    const float* ep = emb + (size_t)n * 256 + c8;
    float4 v0 = *(const float4*)ep;
    float4 v1 = *(const float4*)(ep + 4);
    float vv[8] = {v0.x, v0.y, v0.z, v0.w, v1.x, v1.y, v1.z, v1.w};
    u32 pw[4];
    float s2 = 0.f, r2 = 0.f;
    #pragma unroll
    for (int k = 0; k < 4; ++k) {
        __half h0 = __float2half(vv[2 * k]);
        __half h1 = __float2half(vv[2 * k + 1]);
        float r0 = vv[2 * k] - __half2float(h0);
        float r1 = vv[2 * k + 1] - __half2float(h1);
        s2 = fmaf(vv[2 * k], vv[2 * k], s2);
        s2 = fmaf(vv[2 * k + 1], vv[2 * k + 1], s2);
        r2 = fmaf(r0, r0, r2);
        r2 = fmaf(r1, r1, r2);
        pw[k] = (u32)__half_as_ushort(h0) | ((u32)__half_as_ushort(h1) << 16);
    }
    *(uint4*)(eh + (size_t)n * 256 + c8) = make_uint4(pw[0], pw[1], pw[2], pw[3]);
    #pragma unroll
    for (int off = 16; off > 0; off >>= 1) {
        s2 += __shfl_down(s2, off, 32);
        r2 += __shfl_down(r2, off, 32);
    }
    __shared__ float L1[8], L2[8];
    if ((threadIdx.x & 31) == 0) {
        e2[n] = s2;
        L1[threadIdx.x >> 5] = r2;
        L2[threadIdx.x >> 5] = s2;
    }
    __syncthreads();
    if (threadIdx.x == 0) {
        float a = 0.f, bmax = 0.f;
        #pragma unroll
        for (int i = 0; i < 8; ++i) { a = fmaxf(a, L1[i]); bmax = fmaxf(bmax, L2[i]); }
        emaxl[blockIdx.x] = a;
        emaxe[blockIdx.x] = bmax;
    }
}

// ---------------- K3: z -> fp16(-2*z/30) plane (transpose) + per-token residual-sq partial max ----
__global__ void k_split_z(const float* __restrict__ z, u16* __restrict__ zh,
                          float* __restrict__ zmax_part) {
    int bi = blockIdx.x;                     // grid = 1024
    int b = bi >> 6, rest = bi & 63;
    int c0 = (rest >> 4) * 64, s0 = (rest & 15) * 64;
    __shared__ float ld[64][65];
    __shared__ float red2[64][4];
    __shared__ float rmax[64];
    int tid = threadIdx.x;
    #pragma unroll
    for (int p = 0; p < 16; ++p) {
        int idx = p * 256 + tid;
        int cc = idx >> 6, ss = idx & 63;
        ld[cc][ss] = z[(size_t)b * 262144 + (size_t)(c0 + cc) * 1024 + s0 + ss];
    }
    __syncthreads();
    int ss2 = tid >> 2, cq = tid & 3;
    int t = b * 1024 + s0 + ss2;
    float r2 = 0.f;
    u32 pk[8];
    #pragma unroll
    for (int k = 0; k < 8; ++k) pk[k] = 0;
    #pragma unroll
    for (int j = 0; j < 16; ++j) {
        float v = ld[cq * 16 + j][ss2] * (1.0f / 30.0f);
        __half h = __float2half(v);
        float vh = __half2float(h);
        float r = v - vh;
        r2 = fmaf(r, r, r2);
        __half hs = __float2half(-2.0f * vh);   // exact power-of-2 scale
        pk[j >> 1] |= ((u32)__half_as_ushort(hs)) << ((j & 1) * 16);
    }
    u16* dst = zh + (size_t)t * 256 + c0 + cq * 16;
    *(uint4*)dst = make_uint4(pk[0], pk[1], pk[2], pk[3]);
    *(uint4*)(dst + 8) = make_uint4(pk[4], pk[5], pk[6], pk[7]);
    red2[ss2][cq] = r2;
    __syncthreads();
    if (tid < 64) rmax[tid] = red2[tid][0] + red2[tid][1] + red2[tid][2] + red2[tid][3];
    __syncthreads();
    for (int off = 32; off > 0; off >>= 1) {
        if (tid < off) rmax[tid] = fmaxf(rmax[tid], rmax[tid + off]);
        __syncthreads();
    }
    if (tid == 0) zmax_part[bi] = rmax[0];
}

// ---------------- K4: merged scalar pass: scale + EPS2 + cnt=0 ----------------
__global__ void k_scalars(const float* __restrict__ nrm_part, const float* __restrict__ nrmmax_part,
                          const float* __restrict__ zmax_part, const float* __restrict__ emaxl,
                          const float* __restrict__ emaxe, float* __restrict__ cst,
                          int* __restrict__ cnt) {
    int tid = threadIdx.x;  // 256
    float s = (tid < 64) ? nrm_part[tid] : 0.f;
    float m = (tid < 64) ? nrmmax_part[tid] : 0.f;
    float zm = 0.f, el = 0.f, ee = 0.f;
    for (int i = tid; i < 1024; i += 256) zm = fmaxf(zm, zmax_part[i]);
    for (int i = tid; i < 2048; i += 256) { el = fmaxf(el, emaxl[i]); ee = fmaxf(ee, emaxe[i]); }
    __shared__ float S[256], M[256], Z[256], L[256], E[256];
    S[tid] = s; M[tid] = m; Z[tid] = zm; L[tid] = el; E[tid] = ee;
    __syncthreads();
    for (int off = 128; off > 0; off >>= 1) {
        if (tid < off) {
            S[tid] += S[tid + off];
            M[tid] = fmaxf(M[tid], M[tid + off]);
            Z[tid] = fmaxf(Z[tid], Z[tid + off]);
            L[tid] = fmaxf(L[tid], L[tid + off]);
            E[tid] = fmaxf(E[tid], E[tid + off]);
        }
        __syncthreads();
    }
    if (tid == 0) {
        float pre_len = S[0] * (1.0f / 16384.0f);
        float scale = (pre_len >= FIXLEN) ? (FIXLEN / pre_len) : 1.0f;
        cst[0] = scale;
        cst[1] = 1.0f / scale;
        cst[3] = M[0];
        float maxA  = M[0] * (1.0f / 30.0f);
        float maxEl = sqrtf(L[0]);
        float maxE  = sqrtf(E[0]);
        float maxZl = 2.0f * sqrtf(Z[0]);
        float eps = 2.0f * (maxA * maxEl + maxZl * maxE + maxZl * maxEl) + 0.03f;
        cst[2] = 2.0f * eps;
        cnt[0] = 0;
    }
}

// ---------------- K5: fp16 MFMA GEMM, round-2 shell + rotated counted-vmcnt pipeline ----------
// 256 threads = 4 waves (2M x 2N), wave tile 64x64, block tile 128 tok x 2048 emb.  2 blocks/CU
// (LDS 80 KB, arch-VGPR pressure ~ round-2's 88: acc[4][4] goes to AGPRs; 512-thr variants
// spilled on the 128-arch budget and are abandoned).
// Slice schedule (slice = 128 emb x K=32, global index s = c*8+ks, buffer = s&1):
//   lgkm(0); bar#1 [all waves done reading bcur via last slice's early reads];
//   stage(s+2)->bcur; [ks==0: e2 prefetch, compiler-managed];
//   vmcnt(2) [s+1 landed, s+2 in flight; ks==0 uses vmcnt(6) to leave the 4 e2 loads flying];
//   bar#2 [bnext valid]; MFMA tj0-1; read B'(lo) from bnext; MFMA tj2-3; read B'(hi)+A'.
// Counted waits are robust to compiler-inserted loads: extra outstanding VMEM only makes a
// fixed-N vmcnt stronger, never weaker.  Chunk-boundary argmin (packed 6-bit keys, 3 VALU/out)
// overlaps the early reads at ks==7.
__launch_bounds__(256, 2)
__global__ void k_mfma(const u16* __restrict__ zh, const u16* __restrict__ eh,
                       const float* __restrict__ e2g, const float* __restrict__ cst,
                       u64* __restrict__ pv1, float* __restrict__ pvb2) {
    __shared__ __align__(16) char lds[81920];
    char* sAb = lds;                    // 64 KB: [128 rows][32 slots16], slot^=(row&7) low3
    char* sB0 = lds + 65536;            // 8 KB:  [128 rows][4 slots16], slot^=((row>>1)&3)
    char* sB1 = lds + 73728;            // 8 KB

    int part = blockIdx.x & 7;          // XCD-aligned: one B-part per XCD L2
    int tokT = blockIdx.x >> 3;         // 0..127
    int t0 = tokT * 128;
    int nbase = part * 2048;
    float inv_s = cst[1];
    int tid = threadIdx.x, w = tid >> 6, lane = tid & 63;
    int ml = lane & 15, q = lane >> 4;
    int wm0 = (w & 1) * 64, wn0 = (w >> 1) * 64;
    int x7 = ml & 7;
    int xb = (ml >> 1) & 3;

    // ---- prologue: stage A plane (16 granules/thread), source-XOR swizzle ----
    #pragma unroll
    for (int i = 0; i < 16; ++i) {
        int el = i * 256 + tid;
        int row = el >> 5, j = el & 31;
        int jsrc = (j & 24) | ((j & 7) ^ (row & 7));
        gl_lds16(zh + (size_t)(t0 + row) * 256 + jsrc * 8, sAb + el * 16);
    }
    // stage B slice 0 -> sB0 (all of it), THEN slice 1 -> sB1 (issue order matters for counts)
    #pragma unroll
    for (int i = 0; i < 2; ++i) {
        int el = i * 256 + tid;
        int row = el >> 2, j = el & 3;
        int jsrc = j ^ ((row >> 1) & 3);
        gl_lds16(eh + (size_t)(nbase + row) * 256 + jsrc * 8, sB0 + el * 16);
    }
    #pragma unroll
    for (int i = 0; i < 2; ++i) {
        int el = i * 256 + tid;
        int row = el >> 2, j = el & 3;
        int jsrc = j ^ ((row >> 1) & 3);
        gl_lds16(eh + (size_t)(nbase + row) * 256 + 32 + jsrc * 8, sB1 + el * 16);
    }

    float etb[4], etn[4];
    #pragma unroll
    for (int tj = 0; tj < 4; ++tj) etb[tj] = e2g[nbase + wn0 + tj * 16 + ml];

    float b1[16], b2[16];
    #pragma unroll
    for (int k = 0; k < 16; ++k) { b1[k] = 3.4e38f; b2[k] = 3.4e38f; }

    // A + slice0 landed (slice1's 2 granules may fly; etb handled by compiler waits)
    asm volatile("s_waitcnt vmcnt(2)" ::: "memory");
    __builtin_amdgcn_sched_barrier(0);
    __builtin_amdgcn_s_barrier();

    f32x4 acc[4][4];
    half8 A[4], B[4];
    int slB = q ^ xb;
    int ncol0 = nbase + wn0 + ml;

    // pre-read frags for slice 0
    #pragma unroll
    for (int tj = 0; tj < 4; ++tj)
        B[tj] = *(const half8*)(sB0 + (wn0 + tj * 16 + ml) * 64 + slB * 16);
    {
        int slotA = q ^ x7;
        #pragma unroll
        for (int ti = 0; ti < 4; ++ti)
            A[ti] = *(const half8*)(sAb + (wm0 + ti * 16 + ml) * 512 + slotA * 16);
    }

    #pragma unroll 1
    for (int c = 0; c < 16; ++c) {
        int nc = nbase + c * 128;
        #pragma unroll
        for (int ks = 0; ks < 8; ++ks) {
            char* bcur  = (ks & 1) ? sB1 : sB0;
            char* bnext = (ks & 1) ? sB0 : sB1;
            const bool hasStage = (c < 15) || (ks < 6);
            const bool hasNext  = (c < 15) || (ks < 7);
            const bool hasEtn   = (ks == 0) && (c < 15);
            // frags for this slice (read during previous slice) complete; buffer handoff
            asm volatile("s_waitcnt lgkmcnt(0)" ::: "memory");
            __builtin_amdgcn_sched_barrier(0);
            __builtin_amdgcn_s_barrier();          // #1: all waves done reading bcur
            // stage slice s+2 into bcur
            if (hasStage) {
                int cc2 = (ks >= 6) ? c + 1 : c;
                const int kk2 = (ks + 2) & 7;
                #pragma unroll
                for (int i = 0; i < 2; ++i) {
                    int el = i * 256 + tid;
                    int row = el >> 2, j = el & 3;
                    int jsrc = j ^ ((row >> 1) & 3);
                    gl_lds16(eh + (size_t)(nbase + cc2 * 128 + row) * 256 + kk2 * 32 + jsrc * 8,
                             bcur + el * 16);
                }
            }
            // e2 prefetch for next chunk (4 plain loads; drained by next slice's vmcnt(2))
            if (hasEtn) {
                #pragma unroll
                for (int tj = 0; tj < 4; ++tj)
                    etn[tj] = e2g[nc + 128 + wn0 + tj * 16 + ml];
            }
            // counted wait: slice s+1 landed; s+2 (and e2 at ks==0) stay in flight
            if (hasEtn) {
                asm volatile("s_waitcnt vmcnt(6)" ::: "memory");
            } else if (hasStage) {
                asm volatile("s_waitcnt vmcnt(2)" ::: "memory");
            } else if (ks == 6) {
                asm volatile("s_waitcnt vmcnt(0)" ::: "memory");   // tail: slice 127
            }
            __builtin_amdgcn_sched_barrier(0);
            __builtin_amdgcn_s_barrier();          // #2: bnext fully valid for all waves
            // ---- MFMA group 1 (tj 0..1); ks==0 seeds acc with e2 bias as C ----
            __builtin_amdgcn_s_setprio(1);
            if (ks == 0) {
                #pragma unroll
                for (int tj = 0; tj < 2; ++tj) {
                    float bv = etb[tj] * inv_s;
                    f32x4 cb = {bv, bv, bv, bv};
                    #pragma unroll
                    for (int ti = 0; ti < 4; ++ti)
                        acc[ti][tj] = __builtin_amdgcn_mfma_f32_16x16x32_f16(A[ti], B[tj], cb, 0, 0, 0);
                }
            } else {
                #pragma unroll
                for (int ti = 0; ti < 4; ++ti)
                    #pragma unroll
                    for (int tj = 0; tj < 2; ++tj)
                        acc[ti][tj] = __builtin_amdgcn_mfma_f32_16x16x32_f16(A[ti], B[tj], acc[ti][tj], 0, 0, 0);
            }
            // early reads: B[0..1] for slice s+1 (dead after group 1)
            if (hasNext) {
                #pragma unroll
                for (int tj = 0; tj < 2; ++tj)
                    B[tj] = *(const half8*)(bnext + (wn0 + tj * 16 + ml) * 64 + slB * 16);
            }
            // ---- MFMA group 2 (tj 2..3) ----
            if (ks == 0) {
                #pragma unroll
                for (int tj = 2; tj < 4; ++tj) {
                    float bv = etb[tj] * inv_s;
                    f32x4 cb = {bv, bv, bv, bv};
                    #pragma unroll
                    for (int ti = 0; ti < 4; ++ti)
                        acc[ti][tj] = __builtin_amdgcn_mfma_f32_16x16x32_f16(A[ti], B[tj], cb, 0, 0, 0);
                }
            } else {
                #pragma unroll
                for (int ti = 0; ti < 4; ++ti)
                    #pragma unroll
                    for (int tj = 2; tj < 4; ++tj)
                        acc[ti][tj] = __builtin_amdgcn_mfma_f32_16x16x32_f16(A[ti], B[tj], acc[ti][tj], 0, 0, 0);
            }
            __builtin_amdgcn_s_setprio(0);
            // early reads: B[2..3] + A for slice s+1 (dead after group 2)
            if (hasNext) {
                const int ksn = (ks + 1) & 7;
                int slotA = (ksn >> 1) * 8 + ((((ksn & 1) * 4) + q) ^ x7);
                #pragma unroll
                for (int tj = 2; tj < 4; ++tj)
                    B[tj] = *(const half8*)(bnext + (wn0 + tj * 16 + ml) * 64 + slB * 16);
                #pragma unroll
                for (int ti = 0; ti < 4; ++ti)
                    A[ti] = *(const half8*)(sAb + (wm0 + ti * 16 + ml) * 512 + slotA * 16);
            }
            // ---- chunk-boundary argmin: pure VALU, overlaps the reads above ----
            if (ks == 7) {
                u32 code0 = (u32)(c * 4);
                #pragma unroll
                for (int ti = 0; ti < 4; ++ti)
                    #pragma unroll
                    for (int r = 0; r < 4; ++r) {
                        int k = ti * 4 + r;
                        #pragma unroll
                        for (int tj = 0; tj < 4; ++tj) {
                            u32 kb = (__float_as_uint(acc[ti][tj][r]) & 0xFFFFFFC0u) | (code0 + (u32)tj);
                            float key = __uint_as_float(kb);
                            b2[k] = __builtin_amdgcn_fmed3f(key, b1[k], b2[k]);
                            b1[k] = fminf(b1[k], key);
                        }
                    }
                if (c < 15) {
                    #pragma unroll
                    for (int tj = 0; tj < 4; ++tj) etb[tj] = etn[tj];
                }
            }
        }
    }

    // decode packed indices (once) before cross-lane merge
    int i1[16];
    #pragma unroll
    for (int k = 0; k < 16; ++k) {
        u32 c = __float_as_uint(b1[k]) & 63u;
        i1[k] = ncol0 + (int)((c >> 2) << 7) + (int)((c & 3) << 4);
    }

    // cross-lane merge over ml (masks 1,2,4,8); ties fall to refine via b2
    #pragma unroll
    for (int k = 0; k < 16; ++k) {
        #pragma unroll
        for (int m = 1; m < 16; m <<= 1) {
            float o1 = __shfl_xor(b1[k], m);
            int   oi = __shfl_xor(i1[k], m);
            float o2 = __shfl_xor(b2[k], m);
            float big = fmaxf(b1[k], o1);
            b2[k] = fminf(fminf(b2[k], o2), big);
            bool c = o1 < b1[k];
            i1[k] = c ? oi : i1[k];
            b1[k] = fminf(b1[k], o1);
        }
    }
    __syncthreads();   // all LDS compute reads done; overlay merge arrays on B region
    float* m1s = (float*)sB0;            // [128]
    int*   mis = (int*)(sB0 + 512);      // [128]
    float* m2s = (float*)(sB0 + 1024);   // [128]
    if (w < 2 && ml == 0) {
        #pragma unroll
        for (int ti = 0; ti < 4; ++ti)
            #pragma unroll
            for (int r = 0; r < 4; ++r) {
                int mr = wm0 + ti * 16 + q * 4 + r;
                int k = ti * 4 + r;
                m1s[mr] = b1[k]; mis[mr] = i1[k]; m2s[mr] = b2[k];
            }
    }
    __syncthreads();
    if (w >= 2 && ml == 0) {
        #pragma unroll
        for (int ti = 0; ti < 4; ++ti)
            #pragma unroll
            for (int r = 0; r < 4; ++r) {
                int mr = wm0 + ti * 16 + q * 4 + r;
                int k = ti * 4 + r;
                float a1 = m1s[mr]; int ai = mis[mr]; float a2 = m2s[mr];
                float f1, f2; int fi;
                if (a1 < b1[k]) { f1 = a1; fi = ai; f2 = fminf(a2, b1[k]); }
                else            { f1 = b1[k]; fi = i1[k]; f2 = fminf(b2[k], a1); }
                int t = t0 + mr;
                pv1[(size_t)part * 16384 + t] = ((u64)fkey(f1) << 32) | (u32)fi;
                pvb2[(size_t)part * 16384 + t] = f2;
            }
    }
}

// ---------------- K6: certify per token; build uncertified list ----------------
__global__ void k_refine(const u64* __restrict__ pv1, const float* __restrict__ pvb2,
                         const float* __restrict__ cst, int* __restrict__ bestn,
                         int* __restrict__ list, int* __restrict__ cnt) {
    int t = blockIdx.x * 256 + threadIdx.x;   // grid 64
    float EPS2 = cst[2];
    float amin = 3.4e38f, sec = 3.4e38f; int wi = 0;
    #pragma unroll
    for (int p = 0; p < 8; ++p) {
        u64 u = pv1[(size_t)p * 16384 + t];
        float d1 = fdec((u32)(u >> 32));
        float d2 = pvb2[(size_t)p * 16384 + t];
        if (d1 < amin) { sec = fminf(fminf(sec, amin), d2); amin = d1; wi = (int)(u32)(u & 0xFFFFFFFFull); }
        else sec = fminf(sec, d1);
    }
    bool cert = sec > amin + EPS2;
    if (cert) bestn[t] = wi;
    u64 mask = __ballot(!cert);
    if (mask) {
        int lane = threadIdx.x & 63;
        int leader = __ffsll((long long)mask) - 1;
        int base = 0;
        if (lane == leader) base = atomicAdd(cnt, __popcll(mask));
        base = __shfl(base, leader);
        if (!cert) {
            int rank = __popcll(mask & ((1ull << lane) - 1ull));
            list[base + rank] = t;
        }
    }
}

// ---------------- K7: exact refinement of uncertified tokens, one wave per token ----------------
__global__ void k_refine2(const float* __restrict__ z, const float* __restrict__ emb,
                          const float* __restrict__ e2, const u64* __restrict__ pv1,
                          const float* __restrict__ pvb2, const float* __restrict__ cst,
                          const int* __restrict__ cnt, const int* __restrict__ list,
                          int* __restrict__ bestn) {
    __shared__ float az[4][256];
    int w = threadIdx.x >> 6, lane = threadIdx.x & 63;
    int wid = blockIdx.x * 4 + w;              // grid 64 -> 256 waves
    int C = cnt[0];
    float inv_s = cst[1], EPS2 = cst[2];
    for (int it = wid; it < C; it += 256) {
        int t = list[it];
        int b = t >> 10, hw = t & 1023;
        #pragma unroll
        for (int j = 0; j < 4; ++j)
            az[w][lane + 64 * j] = z[(size_t)b * 262144 + (size_t)(lane + 64 * j) * 1024 + hw] * (1.0f / 30.0f);
        float pb1[8], pb2[8]; int pi1[8];
        float amin = 3.4e38f;
        #pragma unroll
        for (int p = 0; p < 8; ++p) {
            u64 u = pv1[(size_t)p * 16384 + t];
            pb1[p] = fdec((u32)(u >> 32));
            pi1[p] = (int)(u32)(u & 0xFFFFFFFFull);
            pb2[p] = pvb2[(size_t)p * 16384 + t];
            amin = fminf(amin, pb1[p]);
        }
        float thresh = amin + EPS2;
        float bestv = 3.4e38f; int bi = 0x7fffffff;
        for (int p = 0; p < 8; ++p) {
            if (pb2[p] <= thresh) {
                for (int it2 = 0; it2 < 32; ++it2) {
                    int n = p * 2048 + it2 * 64 + lane;
                    const float4* ep = (const float4*)(emb + (size_t)n * 256);
                    float s = 0.f;
                    #pragma unroll 16
                    for (int kk = 0; kk < 64; ++kk) {
                        float4 a4 = *(const float4*)&az[w][kk * 4];
                        float4 e4 = ep[kk];
                        s = fmaf(a4.x, e4.x, s); s = fmaf(a4.y, e4.y, s);
                        s = fmaf(a4.z, e4.z, s); s = fmaf(a4.w, e4.w, s);
                    }
                    float d = fmaf(-2.0f, s, e2[n] * inv_s);
                    if (d < bestv || (d == bestv && n < bi)) { bestv = d; bi = n; }
                }
            } else if (pb1[p] <= thresh) {
                int n = pi1[p];
                float4 a4 = *(const float4*)&az[w][lane * 4];
                float4 e4 = *(const float4*)&emb[(size_t)n * 256 + lane * 4];
                float s = a4.x * e4.x + a4.y * e4.y + a4.z * e4.z + a4.w * e4.w;
                #pragma unroll
                for (int m = 1; m < 64; m <<= 1) s += __shfl_xor(s, m);
                float d = fmaf(-2.0f, s, e2[n] * inv_s);
                if (d < bestv || (d == bestv && n < bi)) { bestv = d; bi = n; }
            }
        }
        #pragma unroll
        for (int m = 1; m < 64; m <<= 1) {
            float ov = __shfl_xor(bestv, m);
            int oi = __shfl_xor(bi, m);
            if (ov < bestv || (ov == bestv && oi < bi)) { bestv = ov; bi = oi; }
        }
        if (lane == 0) bestn[t] = bi;
    }
}

// ---------------- K8: emit z_q, idx, diff partials ----------------
__global__ void k_emit(const float* __restrict__ z, const float* __restrict__ emb,
                       const float* __restrict__ cst, const int* __restrict__ bestn,
                       float* __restrict__ out, float* __restrict__ diff_part) {
    int blk = blockIdx.x;                 // 256
    int cq = blk >> 6, sub = blk & 63;
    int b = sub >> 2;
    int tl = (sub & 3) * 256 + threadIdx.x;
    int t = b * 1024 + tl;
    int bi = bestn[t];
    if (cq == 0) out[4194305 + t] = (float)bi;
    float scale = cst[0];
    const float* er = emb + (size_t)bi * 256 + cq * 64;
    const float* zr = z + (size_t)b * 262144 + (size_t)cq * 65536 + tl;
    float* orow = out + (size_t)b * 262144 + (size_t)cq * 65536 + tl;
    float ds = 0.f;
    #pragma unroll 8
    for (int j = 0; j < 64; ++j) {
        float qv = er[j] * FIXLEN;
        float zt = zr[(size_t)j << 10] * scale;
        float dd = qv - zt;
        ds = fmaf(dd, dd, ds);
        orow[(size_t)j << 10] = qv;
    }
    __shared__ float red[256];
    red[threadIdx.x] = ds;
    __syncthreads();
    for (int off = 128; off > 0; off >>= 1) {
        if (threadIdx.x < off) red[threadIdx.x] += red[threadIdx.x + off];
        __syncthreads();
    }
    if (threadIdx.x == 0) diff_part[blk] = red[0];
}

// ---------------- K9: finalize diff ----------------
__global__ void k_diff(const float* __restrict__ diff_part, float* __restrict__ out) {
    int tid = threadIdx.x;   // 256
    __shared__ float red[256];
    red[tid] = diff_part[tid];
    __syncthreads();
    for (int off = 128; off > 0; off >>= 1) {
        if (tid < off) red[tid] += red[tid + off];
        __syncthreads();
    }
    if (tid == 0) out[4194304] = BETA * red[0] / 4194304.0f;
}

extern "C" void kernel_launch(void* const* d_in, const int* in_sizes, int n_in,
                              void* d_out, int out_size, void* d_ws, size_t ws_size,
                              hipStream_t stream) {
    const float* z   = (const float*)d_in[0];
    const float* emb = (const float*)d_in[1];
    float* out = (float*)d_out;
    char* wsb = (char*)d_ws;

    float* nrm_part    = (float*)(wsb + NRM_OFF);
    float* nrmmax_part = (float*)(wsb + NRMMAX_OFF);
    float* cst         = (float*)(wsb + CST_OFF);
    int*   cnt         = (int*)(wsb + CNT_OFF);
    float* diff_part   = (float*)(wsb + DIFF_OFF);
    float* zmax_part   = (float*)(wsb + ZMAX_OFF);
    float* emaxl       = (float*)(wsb + EMAXL_OFF);
    float* emaxe       = (float*)(wsb + EMAXE_OFF);
    float* e2          = (float*)(wsb + E2_OFF);
    int*   bestn       = (int*)(wsb + BESTN_OFF);
    int*   list        = (int*)(wsb + LIST_OFF);
    u64*   pv1         = (u64*)(wsb + PV1_OFF);
    float* pvb2        = (float*)(wsb + PVB2_OFF);
    u16*   zh          = (u16*)(wsb + ZH_OFF);
    u16*   eh          = (u16*)(wsb + EH_OFF);

    k_norms<<<64, 256, 0, stream>>>(z, nrm_part, nrmmax_part);
    k_split_e<<<2048, 256, 0, stream>>>(emb, eh, e2, emaxl, emaxe);
    k_split_z<<<1024, 256, 0, stream>>>(z, zh, zmax_part);
    k_scalars<<<1, 256, 0, stream>>>(nrm_part, nrmmax_part, zmax_part, emaxl, emaxe, cst, cnt);
    k_mfma<<<1024, 256, 0, stream>>>(zh, eh, e2, cst, pv1, pvb2);
    k_refine<<<64, 256, 0, stream>>>(pv1, pvb2, cst, bestn, list, cnt);
    k_refine2<<<64, 256, 0, stream>>>(z, emb, e2, pv1, pvb2, cst, cnt, list, bestn);
    k_emit<<<256, 256, 0, stream>>>(z, emb, cst, bestn, out, diff_part);
    k_diff<<<1, 256, 0, stream>>>(diff_part, out);
}